// Round 1
// baseline (193.261 us; speedup 1.0000x reference)
//
#include <hip/hip_runtime.h>
#include <hip/hip_fp16.h>

// Problem shape (fixed by reference): B=8, S=4096, D=1024, f32 in/out.
#define B_  8
#define S_  4096
#define D_  1024
#define CH_ 128            // chunks along S
#define L_  (S_ / CH_)     // 32 steps per chunk

// factor = num * 2^-shift, exact in f32 (num < 2^10, shift in [10,12))
__device__ __forceinline__ float dfac(int n, int sh) {
    return (float)n * __uint_as_float((unsigned)(127 - sh) << 23);
}

// ---------------- fast path ----------------
// K1: local scan within chunk; write h_local -> d_out, cumA(fp16) -> ws,
//     chunk aggregates (A, Bv) -> ws.
__global__ __launch_bounds__(256) void k1_fast(
        const float4* __restrict__ x, const int4* __restrict__ nums,
        const int4* __restrict__ shifts, float4* __restrict__ hloc,
        ushort4* __restrict__ cum16, float4* __restrict__ wsA,
        float4* __restrict__ wsB) {
    const int c = blockIdx.x, b = blockIdx.y, t = threadIdx.x;
    float4 A = make_float4(1.f, 1.f, 1.f, 1.f);
    float4 h = make_float4(0.f, 0.f, 0.f, 0.f);
    const size_t base = ((size_t)(b * S_ + c * L_) * D_) >> 2; // float4 idx
    #pragma unroll 8
    for (int s = 0; s < L_; ++s) {
        const size_t i = base + (size_t)s * (D_ / 4) + t;
        const float4 xv = x[i];
        const int4  n  = nums[i];
        const int4  sh = shifts[i];
        const float f0 = dfac(n.x, sh.x), f1 = dfac(n.y, sh.y);
        const float f2 = dfac(n.z, sh.z), f3 = dfac(n.w, sh.w);
        A.x *= f0; A.y *= f1; A.z *= f2; A.w *= f3;
        h.x = fmaf(f0, h.x, xv.x); h.y = fmaf(f1, h.y, xv.y);
        h.z = fmaf(f2, h.z, xv.z); h.w = fmaf(f3, h.w, xv.w);
        hloc[i] = h;
        ushort4 cc;
        cc.x = __half_as_ushort(__float2half_rn(A.x));
        cc.y = __half_as_ushort(__float2half_rn(A.y));
        cc.z = __half_as_ushort(__float2half_rn(A.z));
        cc.w = __half_as_ushort(__float2half_rn(A.w));
        cum16[i] = cc;
    }
    const size_t ai = (size_t)(b * CH_ + c) * (D_ / 4) + t;
    wsA[ai] = A;
    wsB[ai] = h;
}

// K2: exclusive scan of chunk aggregates along chunk axis, per (b,d) chain.
__global__ __launch_bounds__(256) void k2(
        const float* __restrict__ wsA, const float* __restrict__ wsB,
        float* __restrict__ wsC) {
    const int g = blockIdx.x;        // 0..31
    const int b = g >> 2, dt = g & 3;
    const int d = dt * 256 + threadIdx.x;
    float carry = 0.f;
    for (int c = 0; c < CH_; ++c) {
        const size_t i = (size_t)(b * CH_ + c) * D_ + d;
        wsC[i] = carry;                       // exclusive (carry into chunk c)
        carry = fmaf(wsA[i], carry, wsB[i]);  // A*carry + B
    }
}

// K3: h_t = h_local_t + cumA_t * carry
__global__ __launch_bounds__(256) void k3_fast(
        float4* __restrict__ out, const ushort4* __restrict__ cum16,
        const float4* __restrict__ wsC) {
    const int c = blockIdx.x, b = blockIdx.y, t = threadIdx.x;
    if (c == 0) return;  // carry is exactly 0 for the first chunk
    const float4 carry = wsC[(size_t)(b * CH_ + c) * (D_ / 4) + t];
    const size_t base = ((size_t)(b * S_ + c * L_) * D_) >> 2;
    #pragma unroll 8
    for (int s = 0; s < L_; ++s) {
        const size_t i = base + (size_t)s * (D_ / 4) + t;
        float4 h = out[i];
        const ushort4 cc = cum16[i];
        h.x = fmaf(__half2float(__ushort_as_half(cc.x)), carry.x, h.x);
        h.y = fmaf(__half2float(__ushort_as_half(cc.y)), carry.y, h.y);
        h.z = fmaf(__half2float(__ushort_as_half(cc.z)), carry.z, h.z);
        h.w = fmaf(__half2float(__ushort_as_half(cc.w)), carry.w, h.w);
        out[i] = h;
    }
}

// ---------------- slow path (small ws): recompute in pass 3 ----------------
__global__ __launch_bounds__(256) void k1_slow(
        const float4* __restrict__ x, const int4* __restrict__ nums,
        const int4* __restrict__ shifts, float4* __restrict__ wsA,
        float4* __restrict__ wsB) {
    const int c = blockIdx.x, b = blockIdx.y, t = threadIdx.x;
    float4 A = make_float4(1.f, 1.f, 1.f, 1.f);
    float4 h = make_float4(0.f, 0.f, 0.f, 0.f);
    const size_t base = ((size_t)(b * S_ + c * L_) * D_) >> 2;
    #pragma unroll 8
    for (int s = 0; s < L_; ++s) {
        const size_t i = base + (size_t)s * (D_ / 4) + t;
        const float4 xv = x[i];
        const int4  n  = nums[i];
        const int4  sh = shifts[i];
        const float f0 = dfac(n.x, sh.x), f1 = dfac(n.y, sh.y);
        const float f2 = dfac(n.z, sh.z), f3 = dfac(n.w, sh.w);
        A.x *= f0; A.y *= f1; A.z *= f2; A.w *= f3;
        h.x = fmaf(f0, h.x, xv.x); h.y = fmaf(f1, h.y, xv.y);
        h.z = fmaf(f2, h.z, xv.z); h.w = fmaf(f3, h.w, xv.w);
    }
    const size_t ai = (size_t)(b * CH_ + c) * (D_ / 4) + t;
    wsA[ai] = A;
    wsB[ai] = h;
}

__global__ __launch_bounds__(256) void k3_slow(
        const float4* __restrict__ x, const int4* __restrict__ nums,
        const int4* __restrict__ shifts, const float4* __restrict__ wsC,
        float4* __restrict__ out) {
    const int c = blockIdx.x, b = blockIdx.y, t = threadIdx.x;
    float4 h = wsC[(size_t)(b * CH_ + c) * (D_ / 4) + t];
    const size_t base = ((size_t)(b * S_ + c * L_) * D_) >> 2;
    #pragma unroll 8
    for (int s = 0; s < L_; ++s) {
        const size_t i = base + (size_t)s * (D_ / 4) + t;
        const float4 xv = x[i];
        const int4  n  = nums[i];
        const int4  sh = shifts[i];
        const float f0 = dfac(n.x, sh.x), f1 = dfac(n.y, sh.y);
        const float f2 = dfac(n.z, sh.z), f3 = dfac(n.w, sh.w);
        h.x = fmaf(f0, h.x, xv.x); h.y = fmaf(f1, h.y, xv.y);
        h.z = fmaf(f2, h.z, xv.z); h.w = fmaf(f3, h.w, xv.w);
        out[i] = h;
    }
}

extern "C" void kernel_launch(void* const* d_in, const int* in_sizes, int n_in,
                              void* d_out, int out_size, void* d_ws, size_t ws_size,
                              hipStream_t stream) {
    const float4* x  = (const float4*)d_in[0];
    const int4*   nn = (const int4*)d_in[1];
    const int4*   ss = (const int4*)d_in[2];
    float4* out = (float4*)d_out;

    const size_t aggBytes = (size_t)B_ * CH_ * D_ * sizeof(float);       // 4 MiB
    const size_t cumBytes = (size_t)B_ * S_ * D_ * sizeof(unsigned short); // 64 MiB
    char* ws = (char*)d_ws;
    float4* wsA = (float4*)ws;
    float4* wsB = (float4*)(ws + aggBytes);
    float4* wsC = (float4*)(ws + 2 * aggBytes);

    const dim3 g1(CH_, B_);
    const bool fast = ws_size >= 3 * aggBytes + cumBytes;

    if (fast) {
        ushort4* cum16 = (ushort4*)(ws + 3 * aggBytes);
        k1_fast<<<g1, 256, 0, stream>>>(x, nn, ss, out, cum16, wsA, wsB);
        k2<<<32, 256, 0, stream>>>((const float*)wsA, (const float*)wsB,
                                   (float*)wsC);
        k3_fast<<<g1, 256, 0, stream>>>(out, cum16, wsC);
    } else {
        k1_slow<<<g1, 256, 0, stream>>>(x, nn, ss, wsA, wsB);
        k2<<<32, 256, 0, stream>>>((const float*)wsA, (const float*)wsB,
                                   (float*)wsC);
        k3_slow<<<g1, 256, 0, stream>>>(x, nn, ss, wsC, out);
    }
}

// Round 2
// 163.343 us; speedup vs baseline: 1.1832x; 1.1832x over previous
//
#include <hip/hip_runtime.h>
#include <hip/hip_fp16.h>

// Problem shape (fixed by reference): B=8, S=4096, D=1024, f32 in/out.
#define B_  8
#define S_  4096
#define D_  1024
#define CH_ 128            // chunks along S
#define L_  (S_ / CH_)     // 32 steps per chunk

typedef float          f4v __attribute__((ext_vector_type(4)));
typedef int            i4v __attribute__((ext_vector_type(4)));
typedef unsigned short u4v __attribute__((ext_vector_type(4)));

// factor = num * 2^-shift, exact in f32 (num < 2^10, shift in [10,12))
__device__ __forceinline__ float dfac(int n, int sh) {
    return (float)n * __uint_as_float((unsigned)(127 - sh) << 23);
}

// ---------------- fast path ----------------
// K1: local scan within chunk; h_local -> d_out, cumA(fp16) -> ws, chunk
// aggregates (A,B) -> ws. 4-step batched loads, 2-deep pipeline for MLP.
__global__ __launch_bounds__(256, 4) void k1_fast(
        const f4v* __restrict__ x, const i4v* __restrict__ nums,
        const i4v* __restrict__ shifts, f4v* __restrict__ hloc,
        u4v* __restrict__ cum16, f4v* __restrict__ wsA,
        f4v* __restrict__ wsB) {
    const int c = blockIdx.x, b = blockIdx.y, t = threadIdx.x;
    const size_t base = ((size_t)(b * S_ + c * L_) * D_) >> 2; // f4v index
    f4v A = {1.f, 1.f, 1.f, 1.f};
    f4v h = {0.f, 0.f, 0.f, 0.f};

    f4v xb[2][4]; i4v nb[2][4]; i4v sb[2][4];
    #pragma unroll
    for (int u = 0; u < 4; ++u) {
        const size_t i = base + (size_t)u * (D_ / 4) + t;
        xb[0][u] = __builtin_nontemporal_load(x + i);
        nb[0][u] = __builtin_nontemporal_load(nums + i);
        sb[0][u] = __builtin_nontemporal_load(shifts + i);
    }
    #pragma unroll
    for (int j = 0; j < L_ / 4; ++j) {
        const int cur = j & 1;
        if (j + 1 < L_ / 4) {
            #pragma unroll
            for (int u = 0; u < 4; ++u) {
                const size_t i = base + (size_t)((j + 1) * 4 + u) * (D_ / 4) + t;
                xb[cur ^ 1][u] = __builtin_nontemporal_load(x + i);
                nb[cur ^ 1][u] = __builtin_nontemporal_load(nums + i);
                sb[cur ^ 1][u] = __builtin_nontemporal_load(shifts + i);
            }
        }
        #pragma unroll
        for (int u = 0; u < 4; ++u) {
            const size_t i = base + (size_t)(j * 4 + u) * (D_ / 4) + t;
            const f4v xv = xb[cur][u];
            const i4v n  = nb[cur][u];
            const i4v sh = sb[cur][u];
            f4v f;
            f[0] = dfac(n[0], sh[0]); f[1] = dfac(n[1], sh[1]);
            f[2] = dfac(n[2], sh[2]); f[3] = dfac(n[3], sh[3]);
            A *= f;
            h = f * h + xv;          // fused by -ffp-contract
            hloc[i] = h;
            u4v cc;
            cc[0] = __half_as_ushort(__float2half_rn(A[0]));
            cc[1] = __half_as_ushort(__float2half_rn(A[1]));
            cc[2] = __half_as_ushort(__float2half_rn(A[2]));
            cc[3] = __half_as_ushort(__float2half_rn(A[3]));
            cum16[i] = cc;
        }
    }
    const size_t ai = (size_t)(b * CH_ + c) * (D_ / 4) + t;
    wsA[ai] = A;
    wsB[ai] = h;
}

// K2: exclusive scan of chunk aggregates along chunk axis, per (b,d) chain.
__global__ __launch_bounds__(256) void k2(
        const float* __restrict__ wsA, const float* __restrict__ wsB,
        float* __restrict__ wsC) {
    const int g = blockIdx.x;        // 0..31
    const int b = g >> 2, dt = g & 3;
    const int d = dt * 256 + threadIdx.x;
    float carry = 0.f;
    for (int c = 0; c < CH_; ++c) {
        const size_t i = (size_t)(b * CH_ + c) * D_ + d;
        wsC[i] = carry;                       // exclusive (carry into chunk c)
        carry = fmaf(wsA[i], carry, wsB[i]);  // A*carry + B
    }
}

// K3: h_t = h_local_t + cumA_t * carry (chunk 0 skipped: carry == 0)
__global__ __launch_bounds__(256, 4) void k3_fast(
        f4v* __restrict__ out, const u4v* __restrict__ cum16,
        const f4v* __restrict__ wsC) {
    const int c = blockIdx.x + 1, b = blockIdx.y, t = threadIdx.x;
    const f4v carry = wsC[(size_t)(b * CH_ + c) * (D_ / 4) + t];
    const size_t base = ((size_t)(b * S_ + c * L_) * D_) >> 2;

    f4v hb[2][4]; u4v cb[2][4];
    #pragma unroll
    for (int u = 0; u < 4; ++u) {
        const size_t i = base + (size_t)u * (D_ / 4) + t;
        hb[0][u] = out[i];
        cb[0][u] = cum16[i];
    }
    #pragma unroll
    for (int j = 0; j < L_ / 4; ++j) {
        const int cur = j & 1;
        if (j + 1 < L_ / 4) {
            #pragma unroll
            for (int u = 0; u < 4; ++u) {
                const size_t i = base + (size_t)((j + 1) * 4 + u) * (D_ / 4) + t;
                hb[cur ^ 1][u] = out[i];
                cb[cur ^ 1][u] = cum16[i];
            }
        }
        #pragma unroll
        for (int u = 0; u < 4; ++u) {
            const size_t i = base + (size_t)(j * 4 + u) * (D_ / 4) + t;
            f4v h = hb[cur][u];
            const u4v cc = cb[cur][u];
            h[0] = fmaf(__half2float(__ushort_as_half(cc[0])), carry[0], h[0]);
            h[1] = fmaf(__half2float(__ushort_as_half(cc[1])), carry[1], h[1]);
            h[2] = fmaf(__half2float(__ushort_as_half(cc[2])), carry[2], h[2]);
            h[3] = fmaf(__half2float(__ushort_as_half(cc[3])), carry[3], h[3]);
            __builtin_nontemporal_store(h, out + i);
        }
    }
}

// ---------------- slow path (small ws): recompute in pass 3 ----------------
__global__ __launch_bounds__(256) void k1_slow(
        const f4v* __restrict__ x, const i4v* __restrict__ nums,
        const i4v* __restrict__ shifts, f4v* __restrict__ wsA,
        f4v* __restrict__ wsB) {
    const int c = blockIdx.x, b = blockIdx.y, t = threadIdx.x;
    f4v A = {1.f, 1.f, 1.f, 1.f};
    f4v h = {0.f, 0.f, 0.f, 0.f};
    const size_t base = ((size_t)(b * S_ + c * L_) * D_) >> 2;
    #pragma unroll 8
    for (int s = 0; s < L_; ++s) {
        const size_t i = base + (size_t)s * (D_ / 4) + t;
        const f4v xv = x[i];
        const i4v n  = nums[i];
        const i4v sh = shifts[i];
        f4v f;
        f[0] = dfac(n[0], sh[0]); f[1] = dfac(n[1], sh[1]);
        f[2] = dfac(n[2], sh[2]); f[3] = dfac(n[3], sh[3]);
        A *= f;
        h = f * h + xv;
    }
    const size_t ai = (size_t)(b * CH_ + c) * (D_ / 4) + t;
    wsA[ai] = A;
    wsB[ai] = h;
}

__global__ __launch_bounds__(256) void k3_slow(
        const f4v* __restrict__ x, const i4v* __restrict__ nums,
        const i4v* __restrict__ shifts, const f4v* __restrict__ wsC,
        f4v* __restrict__ out) {
    const int c = blockIdx.x, b = blockIdx.y, t = threadIdx.x;
    f4v h = wsC[(size_t)(b * CH_ + c) * (D_ / 4) + t];
    const size_t base = ((size_t)(b * S_ + c * L_) * D_) >> 2;
    #pragma unroll 8
    for (int s = 0; s < L_; ++s) {
        const size_t i = base + (size_t)s * (D_ / 4) + t;
        const f4v xv = x[i];
        const i4v n  = nums[i];
        const i4v sh = shifts[i];
        f4v f;
        f[0] = dfac(n[0], sh[0]); f[1] = dfac(n[1], sh[1]);
        f[2] = dfac(n[2], sh[2]); f[3] = dfac(n[3], sh[3]);
        h = f * h + xv;
        out[i] = h;
    }
}

extern "C" void kernel_launch(void* const* d_in, const int* in_sizes, int n_in,
                              void* d_out, int out_size, void* d_ws, size_t ws_size,
                              hipStream_t stream) {
    const f4v* x  = (const f4v*)d_in[0];
    const i4v* nn = (const i4v*)d_in[1];
    const i4v* ss = (const i4v*)d_in[2];
    f4v* out = (f4v*)d_out;

    const size_t aggBytes = (size_t)B_ * CH_ * D_ * sizeof(float);         // 4 MiB
    const size_t cumBytes = (size_t)B_ * S_ * D_ * sizeof(unsigned short); // 64 MiB
    char* ws = (char*)d_ws;
    f4v* wsA = (f4v*)ws;
    f4v* wsB = (f4v*)(ws + aggBytes);
    f4v* wsC = (f4v*)(ws + 2 * aggBytes);

    const dim3 g1(CH_, B_);
    const bool fast = ws_size >= 3 * aggBytes + cumBytes;

    if (fast) {
        u4v* cum16 = (u4v*)(ws + 3 * aggBytes);
        k1_fast<<<g1, 256, 0, stream>>>(x, nn, ss, out, cum16, wsA, wsB);
        k2<<<32, 256, 0, stream>>>((const float*)wsA, (const float*)wsB,
                                   (float*)wsC);
        k3_fast<<<dim3(CH_ - 1, B_), 256, 0, stream>>>(out, cum16, wsC);
    } else {
        k1_slow<<<g1, 256, 0, stream>>>(x, nn, ss, wsA, wsB);
        k2<<<32, 256, 0, stream>>>((const float*)wsA, (const float*)wsB,
                                   (float*)wsC);
        k3_slow<<<g1, 256, 0, stream>>>(x, nn, ss, wsC, out);
    }
}